// Round 6
// baseline (60.273 us; speedup 1.0000x reference)
//
#include <hip/hip_runtime.h>
#include <math.h>

namespace {

constexpr int D  = 256;
constexpr int H  = 8;

// Async global->LDS, 16B per lane: LDS dest = wave-uniform base + lane*16,
// global src is per-lane (pre-swizzle the source to get swizzled LDS layout).
__device__ inline void async_copy16(float4* lds_dst, const float4* gsrc) {
  __builtin_amdgcn_global_load_lds(
      (const __attribute__((address_space(1))) unsigned int*)(gsrc),
      (__attribute__((address_space(3))) unsigned int*)(lds_dst), 16, 0, 0);
}

// ---------------- Kernel 1: qW[bn,h,e] = sum_d q[bn,d] * W[h,d,e] ----------------
// UNCHANGED (timed ~4 us; profiled ~40 us is a cold-cache replay artifact).
__global__ __launch_bounds__(256) void qw_kernel(
    const float* __restrict__ q, const float* __restrict__ W,
    float* __restrict__ qW) {
  __shared__ float qT[256][20];
  const int tid = threadIdx.x;
  const int bn0 = blockIdx.x * 16;
  const int h   = blockIdx.y;
  for (int i = 0; i < 16; ++i)
    qT[tid][i] = q[(size_t)(bn0 + i) * D + tid];
  __syncthreads();

  const int r0 = (tid >> 6) << 2;
  const int e0 = (tid & 63) << 2;
  float acc[4][4];
  #pragma unroll
  for (int r = 0; r < 4; ++r)
    #pragma unroll
    for (int e = 0; e < 4; ++e) acc[r][e] = 0.f;

  const float4* W4 = reinterpret_cast<const float4*>(W + (size_t)h * D * D);
  const int ecol = e0 >> 2;
  for (int d = 0; d < D; ++d) {
    float4 qv = *reinterpret_cast<const float4*>(&qT[d][r0]);
    float4 wv = W4[d * 64 + ecol];
    const float qa[4] = {qv.x, qv.y, qv.z, qv.w};
    const float wa[4] = {wv.x, wv.y, wv.z, wv.w};
    #pragma unroll
    for (int r = 0; r < 4; ++r)
      #pragma unroll
      for (int e = 0; e < 4; ++e)
        acc[r][e] += qa[r] * wa[e];
  }
  #pragma unroll
  for (int r = 0; r < 4; ++r) {
    float4 o = make_float4(acc[r][0], acc[r][1], acc[r][2], acc[r][3]);
    *reinterpret_cast<float4*>(&qW[(size_t)(bn0 + r0 + r) * (H * D) + h * D + e0]) = o;
  }
}

// ---------------- Kernel 2: scores + chunk-softmax -> attn (2-phase pipelined) ----
// Grid (256, 2) = (bn-group of 4, k-half). Block 256 thr = 4 waves; wave w owns
// softmax chunk c = 4*kh + w = k rows [8c, 8c+8) of each bn. k double-buffered in
// LDS via global_load_lds (source-swizzled ln^i); next bn's k + qW prefetched
// BEFORE computing current bn, so HBM loads stay in flight across the whole
// compute phase (T3 minimal 2-phase; single drain barrier per bn).
__global__ __launch_bounds__(256, 2) void score_kernel(
    const float* __restrict__ qW, const float* __restrict__ kin,
    const float* __restrict__ bin, float* __restrict__ attn_out) {
  __shared__ float4 k_lds[2][32][64];   // 2 x 32 KB
  __shared__ float  qW_lds[H][260];     // 8.3 KB, h-rows staggered across banks
  const int tid  = threadIdx.x;
  const int bn0  = blockIdx.x * 4;
  const int kh   = blockIdx.y;
  const int wid  = tid >> 6;
  const int ln   = tid & 63;
  const int rloc = ln >> 3;
  const int h    = ln & 7;
  const float bias = bin[h];

  // ---- prologue: stage bn0's k (async) + qW (regs -> LDS)
  {
    const float4* kb = reinterpret_cast<const float4*>(kin) +
                       (size_t)bn0 * 4096 + (size_t)(kh * 32 + wid * 8) * 64;
    #pragma unroll
    for (int i = 0; i < 8; ++i)
      async_copy16(&k_lds[0][wid * 8 + i][0], kb + i * 64 + (ln ^ i));
    const float4* qw4 = reinterpret_cast<const float4*>(qW) + (size_t)bn0 * 512;
    float4 q0 = qw4[tid];
    float4 q1 = qw4[tid + 256];
    *reinterpret_cast<float4*>(&qW_lds[tid >> 6][(tid & 63) << 2]) = q0;
    *reinterpret_cast<float4*>(&qW_lds[(tid + 256) >> 6][(tid & 63) << 2]) = q1;
  }
  __syncthreads();   // drains k-stage (vmcnt) + qW LDS writes (lgkm)

  int cur = 0;
  for (int t = 0; t < 4; ++t) {
    const int bn = bn0 + t;

    // ---- issue next-bn prefetches FIRST (in flight during compute below)
    float4 qp0 = make_float4(0.f, 0.f, 0.f, 0.f);
    float4 qp1 = make_float4(0.f, 0.f, 0.f, 0.f);
    if (t < 3) {
      const float4* kb = reinterpret_cast<const float4*>(kin) +
                         (size_t)(bn + 1) * 4096 + (size_t)(kh * 32 + wid * 8) * 64;
      #pragma unroll
      for (int i = 0; i < 8; ++i)
        async_copy16(&k_lds[cur ^ 1][wid * 8 + i][0], kb + i * 64 + (ln ^ i));
      const float4* qw4 = reinterpret_cast<const float4*>(qW) + (size_t)(bn + 1) * 512;
      qp0 = qw4[tid];
      qp1 = qw4[tid + 256];
    }
    __builtin_amdgcn_sched_barrier(0);  // keep prefetch issuance above compute

    // ---- compute scores for current bn (reads k_lds[cur] + qW_lds)
    const float4* a4   = reinterpret_cast<const float4*>(&qW_lds[h][0]);
    const float4* krow = &k_lds[cur][wid * 8 + rloc][0];
    float acc = bias;
    #pragma unroll 8
    for (int e = 0; e < 64; ++e) {
      float4 kv = krow[e ^ rloc];        // undo source swizzle
      float4 av = a4[e];
      acc += av.x * kv.x + av.y * kv.y + av.z * kv.z + av.w * kv.w;
    }

    // ---- softmax across the wave (lane ln holds flat element ln of chunk)
    float m = acc;
    #pragma unroll
    for (int off = 32; off; off >>= 1) m = fmaxf(m, __shfl_xor(m, off, 64));
    float ex = expf(acc - m);
    float s = ex;
    #pragma unroll
    for (int off = 32; off; off >>= 1) s += __shfl_xor(s, off, 64);
    attn_out[(size_t)bn * 512 + (4 * kh + wid) * 64 + ln] = ex / s;

    __syncthreads();   // compute reads done; prefetched k + qW drained
    if (t < 3) {
      *reinterpret_cast<float4*>(&qW_lds[tid >> 6][(tid & 63) << 2]) = qp0;
      *reinterpret_cast<float4*>(&qW_lds[(tid + 256) >> 6][(tid & 63) << 2]) = qp1;
    }
    __syncthreads();   // qW_lds update visible before next compute
    cur ^= 1;
  }
}

// ---------------- Kernel 3: PV ----------------
// v loads issued at kernel start (T14 issue-early), latency hides under wsum.
__global__ __launch_bounds__(256, 2) void pv_kernel(
    const float* __restrict__ vin, const float* __restrict__ attn_in,
    float* __restrict__ out) {
  __shared__ float ws[64];
  __shared__ float s_red[8][32][4];
  const int tid = threadIdx.x;
  const int bn  = blockIdx.x;
  const int dh  = blockIdx.y;

  // issue v loads first: 8 independent, coalesced (2x512B segments/instr)
  const int d4 = tid & 31;
  const int rg = tid >> 5;
  const float4* v4 = reinterpret_cast<const float4*>(vin) +
                     (size_t)bn * 4096 + dh * 32;
  float4 vv[8];
  #pragma unroll
  for (int i = 0; i < 8; ++i) vv[i] = v4[(size_t)(rg + i * 8) * 64 + d4];

  if (tid < 64) {
    const float* ap = attn_in + (size_t)bn * 512 + tid;
    float w = 0.f;
    #pragma unroll
    for (int c = 0; c < 8; ++c) w += ap[c * 64];
    ws[tid] = w;
  }
  __syncthreads();

  float4 acc = make_float4(0.f, 0.f, 0.f, 0.f);
  #pragma unroll
  for (int i = 0; i < 8; ++i) {
    float w = ws[rg + i * 8];
    acc.x += w * vv[i].x; acc.y += w * vv[i].y;
    acc.z += w * vv[i].z; acc.w += w * vv[i].w;
  }
  *reinterpret_cast<float4*>(&s_red[rg][d4][0]) = acc;
  __syncthreads();

  if (tid < 32) {
    float4 o = make_float4(0.f, 0.f, 0.f, 0.f);
    #pragma unroll
    for (int g = 0; g < 8; ++g) {
      float4 r = *reinterpret_cast<const float4*>(&s_red[g][tid][0]);
      o.x += r.x; o.y += r.y; o.z += r.z; o.w += r.w;
    }
    reinterpret_cast<float4*>(out)[(size_t)bn * 64 + dh * 32 + tid] = o;
  }
}

}  // namespace

extern "C" void kernel_launch(void* const* d_in, const int* in_sizes, int n_in,
                              void* d_out, int out_size, void* d_ws, size_t ws_size,
                              hipStream_t stream) {
  const float* q = (const float*)d_in[0];   // (8,128,1,256)
  const float* k = (const float*)d_in[1];   // (8,128,64,256)
  const float* v = (const float*)d_in[2];   // (8,128,64,256)
  const float* W = (const float*)d_in[3];   // (8,256,256)
  const float* b = (const float*)d_in[4];   // (8,)

  float* out  = (float*)d_out;              // output: 262144 f32
  float* attn = out + 262144;               // attn:   524288 f32
  float* qWbuf = (float*)d_ws;              // 1024*2048 f32 = 8 MiB scratch

  hipLaunchKernelGGL(qw_kernel, dim3(64, 8), dim3(256), 0, stream, q, W, qWbuf);
  hipLaunchKernelGGL(score_kernel, dim3(256, 2), dim3(256), 0, stream,
                     qWbuf, k, b, attn);
  hipLaunchKernelGGL(pv_kernel, dim3(1024, 2), dim3(256), 0, stream,
                     v, attn, out);
}

// Round 8
// 53.985 us; speedup vs baseline: 1.1165x; 1.1165x over previous
//
#include <hip/hip_runtime.h>
#include <math.h>

namespace {

constexpr int D = 256;
constexpr int H = 8;

typedef __attribute__((ext_vector_type(8))) short bf16x8;
typedef __attribute__((ext_vector_type(4))) float f32x4;

__device__ inline unsigned short bf16rn(float x) {
  unsigned u = __builtin_bit_cast(unsigned, x);
  u += 0x7fffu + ((u >> 16) & 1u);
  return (unsigned short)(u >> 16);
}
__device__ inline float bf16tof(unsigned short b) {
  return __builtin_bit_cast(float, (unsigned)b << 16);
}

// ---------------- Kernel 1: qW[bn,h,e] = sum_d q[bn,d] * W[h,d,e] ----------------
// REVERTED to the R1-R6 version (validated 6 rounds) to isolate the MFMA score path.
__global__ __launch_bounds__(256) void qw_kernel(
    const float* __restrict__ q, const float* __restrict__ W,
    float* __restrict__ qW) {
  __shared__ float qT[256][20];
  const int tid = threadIdx.x;
  const int bn0 = blockIdx.x * 16;
  const int h   = blockIdx.y;
  for (int i = 0; i < 16; ++i)
    qT[tid][i] = q[(size_t)(bn0 + i) * D + tid];
  __syncthreads();

  const int r0 = (tid >> 6) << 2;
  const int e0 = (tid & 63) << 2;
  float acc[4][4];
  #pragma unroll
  for (int r = 0; r < 4; ++r)
    #pragma unroll
    for (int e = 0; e < 4; ++e) acc[r][e] = 0.f;

  const float4* W4 = reinterpret_cast<const float4*>(W + (size_t)h * D * D);
  const int ecol = e0 >> 2;
  for (int d = 0; d < D; ++d) {
    float4 qv = *reinterpret_cast<const float4*>(&qT[d][r0]);
    float4 wv = W4[d * 64 + ecol];
    const float qa[4] = {qv.x, qv.y, qv.z, qv.w};
    const float wa[4] = {wv.x, wv.y, wv.z, wv.w};
    #pragma unroll
    for (int r = 0; r < 4; ++r)
      #pragma unroll
      for (int e = 0; e < 4; ++e)
        acc[r][e] += qa[r] * wa[e];
  }
  #pragma unroll
  for (int r = 0; r < 4; ++r) {
    float4 o = make_float4(acc[r][0], acc[r][1], acc[r][2], acc[r][3]);
    *reinterpret_cast<float4*>(&qW[(size_t)(bn0 + r0 + r) * (H * D) + h * D + e0]) = o;
  }
}

// ---------------- Kernel 2: scores via split-bf16 MFMA + chunk-softmax ----------------
// Grid (1024, 2) = (bn, kh). 256 thr. All threads reg-stage k (8 coalesced float4)
// + qW (2 float4), convert to bf16 hi/lo, write LDS in MFMA-fragment order.
// Waves 0,1 then do tile 0,1 (16 k-rows each): 8 ksteps x 3 MFMAs (hh, hl, lh),
// softmax in-register over C-frags. Same (g,j)->k placement for A and B, so any
// hardware k-permutation cancels in the contraction.
constexpr int FA_HI = 0;
constexpr int FA_LO = 16640;   // 2 tiles * 8 ks * 1040
constexpr int FB_HI = 33280;
constexpr int FB_LO = 41600;   // + 8*1040
constexpr int SMEM_BYTES = 49920;

__global__ __launch_bounds__(256) void score_kernel(
    const float* __restrict__ qW, const float* __restrict__ kin,
    const float* __restrict__ bin, float* __restrict__ attn_out) {
  __shared__ alignas(16) long long smem_ll[SMEM_BYTES / 8];
  char* sm = reinterpret_cast<char*>(smem_ll);
  const int tid = threadIdx.x;
  const int bn  = blockIdx.x;
  const int kh  = blockIdx.y;
  const int wid = tid >> 6;
  const int ln  = tid & 63;

  // ---- stage: issue all global loads first (10 independent, coalesced)
  const float4* k4 = reinterpret_cast<const float4*>(kin) +
                     (size_t)bn * 4096 + (size_t)kh * 2048;
  float4 kv[8];
  #pragma unroll
  for (int i = 0; i < 8; ++i) kv[i] = k4[tid + 256 * i];
  const float4* qw4 = reinterpret_cast<const float4*>(qW) + (size_t)bn * 512;
  float4 qv0 = qw4[tid];
  float4 qv1 = qw4[tid + 256];

  // ---- zero-fill unwritten B slots (cols 8-15) so masked lanes see 0, not garbage
  {
    const uint4 z = make_uint4(0u, 0u, 0u, 0u);
    #pragma unroll
    for (int i = 0; i < 2; ++i) {
      int idx = tid + 256 * i;              // 0..511
      int region = idx >> 8;                // 0 = hi, 1 = lo
      int rem = idx & 255;
      int ks = rem >> 5, slot = 32 + (rem & 31);
      int off = (region ? FB_LO : FB_HI) + ks * 1040 + slot * 16;
      *reinterpret_cast<uint4*>(sm + off) = z;
    }
  }

  // ---- convert + fragment-order LDS writes
  #pragma unroll
  for (int i = 0; i < 8; ++i) {
    int quad = tid + 256 * i;
    int row = quad >> 6, equad = quad & 63;
    int tile = row >> 4, lrow = row & 15;
    int ks = equad >> 3, g = (equad >> 1) & 3, j0 = (equad & 1) * 4;
    int base = tile * 8320 + ks * 1040 + (lrow * 4 + g) * 16 + j0 * 2;
    float e[4] = {kv[i].x, kv[i].y, kv[i].z, kv[i].w};
    unsigned short h0 = bf16rn(e[0]), h1 = bf16rn(e[1]),
                   h2 = bf16rn(e[2]), h3 = bf16rn(e[3]);
    unsigned short l0 = bf16rn(e[0] - bf16tof(h0)), l1 = bf16rn(e[1] - bf16tof(h1)),
                   l2 = bf16rn(e[2] - bf16tof(h2)), l3 = bf16rn(e[3] - bf16tof(h3));
    uint2 hw = make_uint2((unsigned)h0 | ((unsigned)h1 << 16),
                          (unsigned)h2 | ((unsigned)h3 << 16));
    uint2 lw = make_uint2((unsigned)l0 | ((unsigned)l1 << 16),
                          (unsigned)l2 | ((unsigned)l3 << 16));
    *reinterpret_cast<uint2*>(sm + FA_HI + base) = hw;
    *reinterpret_cast<uint2*>(sm + FA_LO + base) = lw;
  }
  #pragma unroll
  for (int i = 0; i < 2; ++i) {
    int p = tid + 256 * i;
    int hh = p >> 6, equad = p & 63;
    int ks = equad >> 3, g = (equad >> 1) & 3, j0 = (equad & 1) * 4;
    int base = ks * 1040 + (hh * 4 + g) * 16 + j0 * 2;
    float4 qv = i == 0 ? qv0 : qv1;
    float e[4] = {qv.x, qv.y, qv.z, qv.w};
    unsigned short h0 = bf16rn(e[0]), h1 = bf16rn(e[1]),
                   h2 = bf16rn(e[2]), h3 = bf16rn(e[3]);
    unsigned short l0 = bf16rn(e[0] - bf16tof(h0)), l1 = bf16rn(e[1] - bf16tof(h1)),
                   l2 = bf16rn(e[2] - bf16tof(h2)), l3 = bf16rn(e[3] - bf16tof(h3));
    uint2 hw = make_uint2((unsigned)h0 | ((unsigned)h1 << 16),
                          (unsigned)h2 | ((unsigned)h3 << 16));
    uint2 lw = make_uint2((unsigned)l0 | ((unsigned)l1 << 16),
                          (unsigned)l2 | ((unsigned)l3 << 16));
    *reinterpret_cast<uint2*>(sm + FB_HI + base) = hw;
    *reinterpret_cast<uint2*>(sm + FB_LO + base) = lw;
  }
  __syncthreads();
  if (wid >= 2) return;   // waves 2,3 done (staging only)

  // ---- MFMA: wave = tile (16 k-rows), full K=256
  const int T = wid;
  const int slot_r = (ln & 15) * 4 + (ln >> 4);
  const char* paH = sm + FA_HI + T * 8320 + slot_r * 16;
  const char* paL = sm + FA_LO + T * 8320 + slot_r * 16;
  const char* pbH = sm + FB_HI + slot_r * 16;
  const char* pbL = sm + FB_LO + slot_r * 16;
  f32x4 acc = {0.f, 0.f, 0.f, 0.f};
  #pragma unroll
  for (int ks = 0; ks < 8; ++ks) {
    bf16x8 aH = *reinterpret_cast<const bf16x8*>(paH + ks * 1040);
    bf16x8 aL = *reinterpret_cast<const bf16x8*>(paL + ks * 1040);
    bf16x8 bH = *reinterpret_cast<const bf16x8*>(pbH + ks * 1040);
    bf16x8 bL = *reinterpret_cast<const bf16x8*>(pbL + ks * 1040);
    acc = __builtin_amdgcn_mfma_f32_16x16x32_bf16(aH, bH, acc, 0, 0, 0);
    acc = __builtin_amdgcn_mfma_f32_16x16x32_bf16(aH, bL, acc, 0, 0, 0);
    acc = __builtin_amdgcn_mfma_f32_16x16x32_bf16(aL, bH, acc, 0, 0, 0);
  }

  // ---- softmax on C-frags: lane holds rows (ln>>4)*4+r (r=0..3), col = ln&15
  const int col = ln & 15;
  const bool valid = col < 8;
  const float bias = bin[ln & 7];
  float x0 = acc[0] + bias, x1 = acc[1] + bias, x2 = acc[2] + bias, x3 = acc[3] + bias;
  float m = valid ? fmaxf(fmaxf(x0, x1), fmaxf(x2, x3)) : -1e30f;
  m = fmaxf(m, __shfl_xor(m, 1, 64));
  m = fmaxf(m, __shfl_xor(m, 2, 64));
  m = fmaxf(m, __shfl_xor(m, 4, 64));
  m = fmaxf(m, __shfl_xor(m, 16, 64));
  float e0 = valid ? expf(x0 - m) : 0.f;
  float e1 = valid ? expf(x1 - m) : 0.f;
  float e2 = valid ? expf(x2 - m) : 0.f;
  float e3 = valid ? expf(x3 - m) : 0.f;
  float s = e0 + e1 + e2 + e3;
  s += __shfl_xor(s, 1, 64);
  s += __shfl_xor(s, 2, 64);
  s += __shfl_xor(s, 4, 64);
  s += __shfl_xor(s, 16, 64);
  if (valid) {
    float inv = 1.f / s;
    size_t base = (size_t)bn * 512 + (size_t)(kh * 32 + T * 16 + (ln >> 4) * 4) * 8 + col;
    attn_out[base]      = e0 * inv;
    attn_out[base + 8]  = e1 * inv;
    attn_out[base + 16] = e2 * inv;
    attn_out[base + 24] = e3 * inv;
  }
}

// ---------------- Kernel 3: PV ----------------
// Grid (1024). Lane = d-quad (64 quads = full 256-d row -> 1KB coalesced v reads);
// wave w covers rows w+4i. wsum from attn (L2-hot), cross-wave d-reduce in LDS.
__global__ __launch_bounds__(256) void pv_kernel(
    const float* __restrict__ vin, const float* __restrict__ attn_in,
    float* __restrict__ out) {
  __shared__ float wpart[4][64];
  __shared__ float wsum[64];
  __shared__ float s_red[4][260];
  const int tid = threadIdx.x;
  const int bn  = blockIdx.x;
  const int wid = tid >> 6;
  const int ln  = tid & 63;

  float a0 = attn_in[(size_t)bn * 512 + tid];
  float a1 = attn_in[(size_t)bn * 512 + 256 + tid];
  wpart[wid][ln] = a0 + a1;
  __syncthreads();
  if (tid < 64) wsum[tid] = wpart[0][tid] + wpart[1][tid] + wpart[2][tid] + wpart[3][tid];
  __syncthreads();

  const float4* v4 = reinterpret_cast<const float4*>(vin) + (size_t)bn * 4096;
  float4 acc = make_float4(0.f, 0.f, 0.f, 0.f);
  #pragma unroll 8
  for (int i = 0; i < 16; ++i) {
    const int r = wid + 4 * i;
    float w = wsum[r];
    float4 vv = v4[r * 64 + ln];
    acc.x += w * vv.x; acc.y += w * vv.y; acc.z += w * vv.z; acc.w += w * vv.w;
  }
  *reinterpret_cast<float4*>(&s_red[wid][ln << 2]) = acc;
  __syncthreads();

  out[(size_t)bn * D + tid] =
      s_red[0][tid] + s_red[1][tid] + s_red[2][tid] + s_red[3][tid];
}

}  // namespace

extern "C" void kernel_launch(void* const* d_in, const int* in_sizes, int n_in,
                              void* d_out, int out_size, void* d_ws, size_t ws_size,
                              hipStream_t stream) {
  const float* q = (const float*)d_in[0];   // (8,128,1,256)
  const float* k = (const float*)d_in[1];   // (8,128,64,256)
  const float* v = (const float*)d_in[2];   // (8,128,64,256)
  const float* W = (const float*)d_in[3];   // (8,256,256)
  const float* b = (const float*)d_in[4];   // (8,)

  float* out  = (float*)d_out;              // output: 262144 f32
  float* attn = out + 262144;               // attn:   524288 f32
  float* qWbuf = (float*)d_ws;              // 1024*2048 f32 = 8 MiB scratch

  hipLaunchKernelGGL(qw_kernel, dim3(64, 8), dim3(256), 0, stream, q, W, qWbuf);
  hipLaunchKernelGGL(score_kernel, dim3(1024, 2), dim3(256), 0, stream,
                     qWbuf, k, b, attn);
  hipLaunchKernelGGL(pv_kernel, dim3(1024), dim3(256), 0, stream,
                     v, attn, out);
}

// Round 9
// 49.000 us; speedup vs baseline: 1.2300x; 1.1017x over previous
//
#include <hip/hip_runtime.h>
#include <math.h>

namespace {

constexpr int D = 256;
constexpr int H = 8;

typedef __attribute__((ext_vector_type(8))) short bf16x8;
typedef __attribute__((ext_vector_type(4))) float f32x4;

__device__ inline unsigned short bf16rn(float x) {
  unsigned u = __builtin_bit_cast(unsigned, x);
  u += 0x7fffu + ((u >> 16) & 1u);
  return (unsigned short)(u >> 16);
}
__device__ inline float bf16tof(unsigned short b) {
  return __builtin_bit_cast(float, (unsigned)b << 16);
}

// Async global->LDS, 16B per lane: LDS dest = wave-uniform base + lane*16.
__device__ inline void async_copy16(float4* lds_dst, const float4* gsrc) {
  __builtin_amdgcn_global_load_lds(
      (const __attribute__((address_space(1))) unsigned int*)(gsrc),
      (__attribute__((address_space(3))) unsigned int*)(lds_dst), 16, 0, 0);
}

// ---------------- Kernel 1: qW[bn,h,e] = sum_d q[bn,d] * W[h,d,e] ----------------
// grid (64,8), 256 thr. W[h] streamed in 16-row chunks via global_load_lds,
// double-buffered (prefetch c+1 before computing c, one barrier per chunk) so the
// inner loop is pure ds_read_b128 + FMA (VALU-bound, no global latency chain).
// Wave wid owns bn rows wid*4..wid*4+3 -> qT read is wave-uniform broadcast.
__global__ __launch_bounds__(256) void qw_kernel(
    const float* __restrict__ q, const float* __restrict__ W,
    float* __restrict__ qW) {
  __shared__ float qT[256][20];       // [d][bn-row], 20 KB; stride 80B, b128-aligned
  __shared__ float Wc[2][16][256];    // 2 x 16 KB W chunks (gload_lds dest: linear)
  const int tid = threadIdx.x;
  const int bn0 = blockIdx.x * 16;
  const int h   = blockIdx.y;
  const int wid = tid >> 6;
  const int ln  = tid & 63;

  // prologue: issue W chunk 0 (rows 0..15; wave w -> rows w*4..w*4+3) ...
  const float4* Wh4 = reinterpret_cast<const float4*>(W + (size_t)h * D * D);
  #pragma unroll
  for (int i = 0; i < 4; ++i) {
    const int row = wid * 4 + i;
    async_copy16(reinterpret_cast<float4*>(&Wc[0][row][0]),
                 Wh4 + (size_t)row * 64 + ln);
  }
  // ... then stage qT (loads overlap the async W copies)
  for (int i = 0; i < 16; ++i)
    qT[tid][i] = q[(size_t)(bn0 + i) * D + tid];
  __syncthreads();   // drains W chunk 0 (vmcnt) + qT writes (lgkm)

  const int r0 = wid << 2;            // bn rows r0..r0+3 (wave-uniform)
  const int e4 = ln;                  // e-quad 0..63
  float acc[4][4];
  #pragma unroll
  for (int r = 0; r < 4; ++r)
    #pragma unroll
    for (int e = 0; e < 4; ++e) acc[r][e] = 0.f;

  int buf = 0;
  for (int c = 0; c < 16; ++c) {
    // prefetch next chunk into buf^1 (in flight during compute below)
    if (c < 15) {
      #pragma unroll
      for (int i = 0; i < 4; ++i) {
        const int row = wid * 4 + i;
        async_copy16(reinterpret_cast<float4*>(&Wc[buf ^ 1][row][0]),
                     Wh4 + (size_t)((c + 1) * 16 + row) * 64 + ln);
      }
    }
    __builtin_amdgcn_sched_barrier(0);

    #pragma unroll
    for (int dl = 0; dl < 16; ++dl) {
      const int d = c * 16 + dl;
      float4 qv = *reinterpret_cast<const float4*>(&qT[d][r0]);       // broadcast
      float4 wv = *reinterpret_cast<const float4*>(&Wc[buf][dl][e4 << 2]);
      const float qa[4] = {qv.x, qv.y, qv.z, qv.w};
      const float wa[4] = {wv.x, wv.y, wv.z, wv.w};
      #pragma unroll
      for (int r = 0; r < 4; ++r)
        #pragma unroll
        for (int e = 0; e < 4; ++e)
          acc[r][e] += qa[r] * wa[e];
    }
    __syncthreads();   // compute reads of buf done; prefetch into buf^1 drained
    buf ^= 1;
  }

  #pragma unroll
  for (int r = 0; r < 4; ++r) {
    float4 o = make_float4(acc[r][0], acc[r][1], acc[r][2], acc[r][3]);
    *reinterpret_cast<float4*>(&qW[(size_t)(bn0 + r0 + r) * (H * D) + h * D + (e4 << 2)]) = o;
  }
}

// ---------------- Kernel 2: scores via split-bf16 MFMA + chunk-softmax ----------------
// (byte-identical to R8 — verified)
constexpr int FA_HI = 0;
constexpr int FA_LO = 16640;   // 2 tiles * 8 ks * 1040
constexpr int FB_HI = 33280;
constexpr int FB_LO = 41600;   // + 8*1040
constexpr int SMEM_BYTES = 49920;

__global__ __launch_bounds__(256) void score_kernel(
    const float* __restrict__ qW, const float* __restrict__ kin,
    const float* __restrict__ bin, float* __restrict__ attn_out) {
  __shared__ alignas(16) long long smem_ll[SMEM_BYTES / 8];
  char* sm = reinterpret_cast<char*>(smem_ll);
  const int tid = threadIdx.x;
  const int bn  = blockIdx.x;
  const int kh  = blockIdx.y;
  const int wid = tid >> 6;
  const int ln  = tid & 63;

  // ---- stage: issue all global loads first (10 independent, coalesced)
  const float4* k4 = reinterpret_cast<const float4*>(kin) +
                     (size_t)bn * 4096 + (size_t)kh * 2048;
  float4 kv[8];
  #pragma unroll
  for (int i = 0; i < 8; ++i) kv[i] = k4[tid + 256 * i];
  const float4* qw4 = reinterpret_cast<const float4*>(qW) + (size_t)bn * 512;
  float4 qv0 = qw4[tid];
  float4 qv1 = qw4[tid + 256];

  // ---- zero-fill unwritten B slots (cols 8-15)
  {
    const uint4 z = make_uint4(0u, 0u, 0u, 0u);
    #pragma unroll
    for (int i = 0; i < 2; ++i) {
      int idx = tid + 256 * i;
      int region = idx >> 8;
      int rem = idx & 255;
      int ks = rem >> 5, slot = 32 + (rem & 31);
      int off = (region ? FB_LO : FB_HI) + ks * 1040 + slot * 16;
      *reinterpret_cast<uint4*>(sm + off) = z;
    }
  }

  // ---- convert + fragment-order LDS writes
  #pragma unroll
  for (int i = 0; i < 8; ++i) {
    int quad = tid + 256 * i;
    int row = quad >> 6, equad = quad & 63;
    int tile = row >> 4, lrow = row & 15;
    int ks = equad >> 3, g = (equad >> 1) & 3, j0 = (equad & 1) * 4;
    int base = tile * 8320 + ks * 1040 + (lrow * 4 + g) * 16 + j0 * 2;
    float e[4] = {kv[i].x, kv[i].y, kv[i].z, kv[i].w};
    unsigned short h0 = bf16rn(e[0]), h1 = bf16rn(e[1]),
                   h2 = bf16rn(e[2]), h3 = bf16rn(e[3]);
    unsigned short l0 = bf16rn(e[0] - bf16tof(h0)), l1 = bf16rn(e[1] - bf16tof(h1)),
                   l2 = bf16rn(e[2] - bf16tof(h2)), l3 = bf16rn(e[3] - bf16tof(h3));
    uint2 hw = make_uint2((unsigned)h0 | ((unsigned)h1 << 16),
                          (unsigned)h2 | ((unsigned)h3 << 16));
    uint2 lw = make_uint2((unsigned)l0 | ((unsigned)l1 << 16),
                          (unsigned)l2 | ((unsigned)l3 << 16));
    *reinterpret_cast<uint2*>(sm + FA_HI + base) = hw;
    *reinterpret_cast<uint2*>(sm + FA_LO + base) = lw;
  }
  #pragma unroll
  for (int i = 0; i < 2; ++i) {
    int p = tid + 256 * i;
    int hh = p >> 6, equad = p & 63;
    int ks = equad >> 3, g = (equad >> 1) & 3, j0 = (equad & 1) * 4;
    int base = ks * 1040 + (hh * 4 + g) * 16 + j0 * 2;
    float4 qv = i == 0 ? qv0 : qv1;
    float e[4] = {qv.x, qv.y, qv.z, qv.w};
    unsigned short h0 = bf16rn(e[0]), h1 = bf16rn(e[1]),
                   h2 = bf16rn(e[2]), h3 = bf16rn(e[3]);
    unsigned short l0 = bf16rn(e[0] - bf16tof(h0)), l1 = bf16rn(e[1] - bf16tof(h1)),
                   l2 = bf16rn(e[2] - bf16tof(h2)), l3 = bf16rn(e[3] - bf16tof(h3));
    uint2 hw = make_uint2((unsigned)h0 | ((unsigned)h1 << 16),
                          (unsigned)h2 | ((unsigned)h3 << 16));
    uint2 lw = make_uint2((unsigned)l0 | ((unsigned)l1 << 16),
                          (unsigned)l2 | ((unsigned)l3 << 16));
    *reinterpret_cast<uint2*>(sm + FB_HI + base) = hw;
    *reinterpret_cast<uint2*>(sm + FB_LO + base) = lw;
  }
  __syncthreads();
  if (wid >= 2) return;

  // ---- MFMA: wave = tile (16 k-rows), full K=256
  const int T = wid;
  const int slot_r = (ln & 15) * 4 + (ln >> 4);
  const char* paH = sm + FA_HI + T * 8320 + slot_r * 16;
  const char* paL = sm + FA_LO + T * 8320 + slot_r * 16;
  const char* pbH = sm + FB_HI + slot_r * 16;
  const char* pbL = sm + FB_LO + slot_r * 16;
  f32x4 acc = {0.f, 0.f, 0.f, 0.f};
  #pragma unroll
  for (int ks = 0; ks < 8; ++ks) {
    bf16x8 aH = *reinterpret_cast<const bf16x8*>(paH + ks * 1040);
    bf16x8 aL = *reinterpret_cast<const bf16x8*>(paL + ks * 1040);
    bf16x8 bH = *reinterpret_cast<const bf16x8*>(pbH + ks * 1040);
    bf16x8 bL = *reinterpret_cast<const bf16x8*>(pbL + ks * 1040);
    acc = __builtin_amdgcn_mfma_f32_16x16x32_bf16(aH, bH, acc, 0, 0, 0);
    acc = __builtin_amdgcn_mfma_f32_16x16x32_bf16(aH, bL, acc, 0, 0, 0);
    acc = __builtin_amdgcn_mfma_f32_16x16x32_bf16(aL, bH, acc, 0, 0, 0);
  }

  // ---- softmax on C-frags
  const int col = ln & 15;
  const bool valid = col < 8;
  const float bias = bin[ln & 7];
  float x0 = acc[0] + bias, x1 = acc[1] + bias, x2 = acc[2] + bias, x3 = acc[3] + bias;
  float m = valid ? fmaxf(fmaxf(x0, x1), fmaxf(x2, x3)) : -1e30f;
  m = fmaxf(m, __shfl_xor(m, 1, 64));
  m = fmaxf(m, __shfl_xor(m, 2, 64));
  m = fmaxf(m, __shfl_xor(m, 4, 64));
  m = fmaxf(m, __shfl_xor(m, 16, 64));
  float e0 = valid ? expf(x0 - m) : 0.f;
  float e1 = valid ? expf(x1 - m) : 0.f;
  float e2 = valid ? expf(x2 - m) : 0.f;
  float e3 = valid ? expf(x3 - m) : 0.f;
  float s = e0 + e1 + e2 + e3;
  s += __shfl_xor(s, 1, 64);
  s += __shfl_xor(s, 2, 64);
  s += __shfl_xor(s, 4, 64);
  s += __shfl_xor(s, 16, 64);
  if (valid) {
    float inv = 1.f / s;
    size_t base = (size_t)bn * 512 + (size_t)(kh * 32 + T * 16 + (ln >> 4) * 4) * 8 + col;
    attn_out[base]      = e0 * inv;
    attn_out[base + 8]  = e1 * inv;
    attn_out[base + 16] = e2 * inv;
    attn_out[base + 24] = e3 * inv;
  }
}

// ---------------- Kernel 3: PV ----------------
// (byte-identical to R8 — verified)
__global__ __launch_bounds__(256) void pv_kernel(
    const float* __restrict__ vin, const float* __restrict__ attn_in,
    float* __restrict__ out) {
  __shared__ float wpart[4][64];
  __shared__ float wsum[64];
  __shared__ float s_red[4][260];
  const int tid = threadIdx.x;
  const int bn  = blockIdx.x;
  const int wid = tid >> 6;
  const int ln  = tid & 63;

  float a0 = attn_in[(size_t)bn * 512 + tid];
  float a1 = attn_in[(size_t)bn * 512 + 256 + tid];
  wpart[wid][ln] = a0 + a1;
  __syncthreads();
  if (tid < 64) wsum[tid] = wpart[0][tid] + wpart[1][tid] + wpart[2][tid] + wpart[3][tid];
  __syncthreads();

  const float4* v4 = reinterpret_cast<const float4*>(vin) + (size_t)bn * 4096;
  float4 acc = make_float4(0.f, 0.f, 0.f, 0.f);
  #pragma unroll 8
  for (int i = 0; i < 16; ++i) {
    const int r = wid + 4 * i;
    float w = wsum[r];
    float4 vv = v4[r * 64 + ln];
    acc.x += w * vv.x; acc.y += w * vv.y; acc.z += w * vv.z; acc.w += w * vv.w;
  }
  *reinterpret_cast<float4*>(&s_red[wid][ln << 2]) = acc;
  __syncthreads();

  out[(size_t)bn * D + tid] =
      s_red[0][tid] + s_red[1][tid] + s_red[2][tid] + s_red[3][tid];
}

}  // namespace

extern "C" void kernel_launch(void* const* d_in, const int* in_sizes, int n_in,
                              void* d_out, int out_size, void* d_ws, size_t ws_size,
                              hipStream_t stream) {
  const float* q = (const float*)d_in[0];   // (8,128,1,256)
  const float* k = (const float*)d_in[1];   // (8,128,64,256)
  const float* v = (const float*)d_in[2];   // (8,128,64,256)
  const float* W = (const float*)d_in[3];   // (8,256,256)
  const float* b = (const float*)d_in[4];   // (8,)

  float* out  = (float*)d_out;              // output: 262144 f32
  float* attn = out + 262144;               // attn:   524288 f32
  float* qWbuf = (float*)d_ws;              // 1024*2048 f32 = 8 MiB scratch

  hipLaunchKernelGGL(qw_kernel, dim3(64, 8), dim3(256), 0, stream, q, W, qWbuf);
  hipLaunchKernelGGL(score_kernel, dim3(1024, 2), dim3(256), 0, stream,
                     qWbuf, k, b, attn);
  hipLaunchKernelGGL(pv_kernel, dim3(1024), dim3(256), 0, stream,
                     v, attn, out);
}